// Round 7
// baseline (55.951 us; speedup 1.0000x reference)
//
#include <hip/hip_runtime.h>

#define Cc 384
#define Hh 56
#define Ww 56
#define PLANE (Hh*Ww)        // 3136 floats
#define NF4 14               // float4s per row
#define NBLK 1536            // 384 channels x 4 batch-groups
#define NPL 8                // batches per block: 1536*8 = 12288 planes

typedef short short8 __attribute__((ext_vector_type(8)));
typedef float f32x4  __attribute__((ext_vector_type(4)));
typedef unsigned int u32;
typedef u32 u32x2 __attribute__((ext_vector_type(2)));
struct __align__(16) f4 { float x, y, z, w; };

__device__ __forceinline__ u32 cvtpk_bf16(float a, float b) {
    u32 d; asm("v_cvt_pk_bf16_f32 %0, %1, %2" : "=v"(d) : "v"(a), "v"(b));
    return d;   // lo=bf16(a), hi=bf16(b), RNE
}
// 16B-block swizzle within a 128B Xt row (8 blocks): good for the staging
// scatter and the b128 frag reads (w = 16ni+l15).
__device__ __forceinline__ int swz(int w) { return (w ^ (w >> 2)) & 7; }

// out = A(56x56 circulant) * X(56x56) per plane, padded to 64^3, bf16 MFMA.
// R14: both HBM streams contiguous -> 58.0us.
// R16 (56.6): Xt stored bf16 -> B-frag is ONE ds_read_b128.
// R17 (54.1): persistent blocks, next-plane loads prefetched under MFMA.
// R18 (53.9, neutral): lgkmcnt-only barrier -> vmcnt drain wasn't the cost.
// R19 FAILED (race w/ asm barrier); R20 (53.7, neutral): quad staging
//   (scatter 196->16 DS wave-instrs) -> DS is NOT the binding pipe.
// Ceiling model (R21): fabric traffic = 154MB read + 150.5MB write = 304MB
//   @ 6.29TB/s copy ceiling -> 48.3us floor; we're at 90%.
// R21 (this round): channel-persistent remap. NBLK=1536=384*4: each block
//   owns ONE channel across 8 batches -> wgt/pe/bias/wt2/A-frags loop-
//   invariant. A-frag build (the bank-conflict + VALU hot spot) runs once
//   per block, not per plane; ISSUE is x-only. All proven phase internals
//   byte-identical. Frees issue slots -> higher fabric duty-cycle.
// waves_per_eu(4,4): the only codegen mode without the VGPR-24 pathology.
__global__ __launch_bounds__(256) __attribute__((amdgpu_waves_per_eu(4, 4)))
void parc_kernel(const float* __restrict__ x, const float* __restrict__ pe,
                 const float* __restrict__ wgt, const float* __restrict__ bias,
                 float* __restrict__ out)
{
    __shared__ __align__(16) unsigned short Xt16[64 * 64]; // [w][m] bf16, swizzled 16B blocks (8KB)
    __shared__ __align__(16) float Cb[56 * 60];            // [h][w] stride 60 dwords (13.4KB)
    __shared__ unsigned short wt2[112];                    // wt[k%56] bf16, single buffer

    const int t   = threadIdx.x;
    const int blk = blockIdx.x;
    const int c    = blk % Cc;                             // fixed channel for this block
    const int bgrp = blk / Cc;                             // 0..3
    const size_t bc0 = (size_t)(bgrp * NPL) * Cc + c;      // first plane; step = Cc

    // quad staging geometry (t<196): hg in 0..13, w4q in 0..13
    const int hg = t / NF4, w4q = t % NF4;
    const int Fq = 56 * hg + w4q;                          // f4 index of row 4hg, this w4
    const int kw = t >= Hh ? t - Hh : t;                   // weight dup index (t<112)
    const int l = t & 63, wvi = t >> 6, l15 = l & 15, g = l >> 4;

    // ---- one-time zeroing (scatter never touches these cells):
    //      (a) m-pad (logical m-block 7) of ALL rows: k>=56 terms exact 0.
    //      (b) w-pad rows 56..63 entirely: no garbage bf16 into MFMA.
    {
        const int w = t >> 2, j = t & 3;
        const int blkz = 7 ^ swz(w);                       // logical m-block 7
        *reinterpret_cast<u32*>((char*)Xt16 + 128 * w + 16 * blkz + 4 * j) = 0u;
        const int wz = 56 + (t >> 5);                      // rows 56..63, full 128B
        *reinterpret_cast<u32*>((char*)Xt16 + 128 * wz + 4 * (t & 31)) = 0u;
    }

    // ---- channel-constant loads (once per block) ----
    float p0 = 0.f, p1 = 0.f, p2 = 0.f, p3 = 0.f;
    if (t < 196) {
        const float* __restrict__ pec = pe + c * Hh;
        p0 = pec[4 * hg]; p1 = pec[4 * hg + 1]; p2 = pec[4 * hg + 2]; p3 = pec[4 * hg + 3];
    }
    const float bz = bias[c];
    if (t < 112) wt2[t] = (unsigned short)(cvtpk_bf16(wgt[c * Hh + kw], 0.f) & 0xffffu);

    f32x4 v0 = {}, v1 = {}, v2 = {}, v3 = {};

    // issue next-plane x loads (registers only; no LDS touch)
    #define ISSUE(BC) { \
        const f32x4* __restrict__ xin = reinterpret_cast<const f32x4*>(x) + (size_t)(BC) * (PLANE / 4); \
        if (t < 196) { \
            v0 = xin[Fq]; v1 = xin[Fq + 14]; v2 = xin[Fq + 28]; v3 = xin[Fq + 42]; \
        } }

    // scatter: 4 ds_write_b64 per thread (4 consecutive m per w-row),
    // conflict-free minimum (14 distinct (blk,sub8) pairs tile the banks)
    #define SCATTER() { \
        if (t < 196) { \
            const int blkb = hg >> 1, sub8 = 8 * (hg & 1); \
            _Pragma("unroll") \
            for (int q = 0; q < 4; ++q) { \
                const int w = 4 * w4q + q; \
                u32x2 d; \
                d[0] = cvtpk_bf16(v0[q] + p0, v1[q] + p1); \
                d[1] = cvtpk_bf16(v2[q] + p2, v3[q] + p3); \
                *reinterpret_cast<u32x2*>((char*)Xt16 + 128 * w + 16 * (blkb ^ swz(w)) + sub8) = d; \
            } \
        } }

    // ---- prologue: plane 0 ----
    ISSUE(bc0)
    SCATTER()
    __syncthreads();

    // ---- A-frags ONCE (loop-invariant: same channel all planes) ----
    // A[h][m] = wt[(m-h)%56]; lane row h=16wvi+l15, k(m)=8g+j+32step
    short8 afr[2];
    #pragma unroll
    for (int step = 0; step < 2; ++step) {
        #pragma unroll
        for (int j = 0; j < 8; ++j) {
            int idx = 32 * step + 8 * g + j - 16 * wvi - l15 + 56;
            idx = idx < 0 ? 0 : (idx > 111 ? 111 : idx);   // pad m>=56 hits zeroed X cols
            afr[step][j] = (short)wt2[idx];
        }
    }

    for (int it = 0; it < NPL; ++it) {
        const size_t bc_cur = bc0 + (size_t)it * Cc;

        // prefetch: next plane's x loads fly under MFMA + store phases
        if (it + 1 < NPL) { ISSUE(bc0 + (size_t)(it + 1) * Cc) }

        f32x4 acc[4];
        #pragma unroll
        for (int ni = 0; ni < 4; ++ni) acc[ni] = (f32x4){bz, bz, bz, bz};

        #pragma unroll
        for (int step = 0; step < 2; ++step) {
            #pragma unroll
            for (int ni = 0; ni < 4; ++ni) {
                const int w = 16 * ni + l15;              // B col n = l15
                const int blk0 = g + 4 * step;            // m0 = 8g+32step
                const short8 bfr = *reinterpret_cast<const short8*>(
                    (char*)Xt16 + 128 * w + 16 * (blk0 ^ swz(w)));
                acc[ni] = __builtin_amdgcn_mfma_f32_16x16x32_bf16(afr[step], bfr, acc[ni], 0, 0, 0);
            }
        }

        // ---- D (col=l15, row=4g+reg) -> Cb[h][w] (stride 60: 2-way banks) ----
        #pragma unroll
        for (int ni = 0; ni < 4; ++ni) {
            const int wcol = 16 * ni + l15;
            #pragma unroll
            for (int r = 0; r < 4; ++r) {
                const int h = 16 * wvi + 4 * g + r;
                if (h < Hh && wcol < Ww) Cb[60 * h + wcol] = acc[ni][r];
            }
        }
        __syncthreads();     // B2: Cb visible; plane-it Xt16 reads retired

        // ---- out stores: linear f4 => 1KB contiguous/wave-instr ----
        f4* __restrict__ op = reinterpret_cast<f4*>(out) + bc_cur * (PLANE / 4);
        #define GETST(U) { \
            const int rr = (U) / NF4, ww4 = (U) % NF4; \
            op[(U)] = *reinterpret_cast<const f4*>((char*)Cb + 240 * rr + 16 * ww4); }
        GETST(t)
        GETST(t + 256)
        GETST(t + 512)
        if (t < 16) { GETST(t + 768) }
        #undef GETST

        if (it + 1 < NPL) {
            SCATTER()            // prefetched loads land here (compiler vmcnt wait)
            __syncthreads();     // B1: Xt16 visible; Cb reads retired before next writes
        }
    }
    #undef SCATTER
    #undef ISSUE
}

extern "C" void kernel_launch(void* const* d_in, const int* in_sizes, int n_in,
                              void* d_out, int out_size, void* d_ws, size_t ws_size,
                              hipStream_t stream) {
    const float* x  = (const float*)d_in[0];
    const float* pe = (const float*)d_in[1];
    const float* w  = (const float*)d_in[2];
    const float* b  = (const float*)d_in[3];
    float* out      = (float*)d_out;

    parc_kernel<<<dim3(NBLK), 256, 0, stream>>>(x, pe, w, b, out);
}

// Round 8
// 54.849 us; speedup vs baseline: 1.0201x; 1.0201x over previous
//
#include <hip/hip_runtime.h>

#define Cc 384
#define Hh 56
#define Ww 56
#define PLANE (Hh*Ww)        // 3136 floats
#define NF4 14               // float4s per row
#define NBLK 3072            // 384 channels x 8 batch-groups
#define NPL 4                // batches per block: 3072*4 = 12288 planes
                             // 3072/256 CU = 12 blocks/CU = 3 FULL generations
                             // of 4 resident (waves_per_eu(4,4) -> 16 waves/CU).
                             // R21's 1536 (6/CU) left gen-2 at half residency.

typedef short short8 __attribute__((ext_vector_type(8)));
typedef float f32x4  __attribute__((ext_vector_type(4)));
typedef unsigned int u32;
typedef u32 u32x2 __attribute__((ext_vector_type(2)));
struct __align__(16) f4 { float x, y, z, w; };

__device__ __forceinline__ u32 cvtpk_bf16(float a, float b) {
    u32 d; asm("v_cvt_pk_bf16_f32 %0, %1, %2" : "=v"(d) : "v"(a), "v"(b));
    return d;   // lo=bf16(a), hi=bf16(b), RNE
}
// 16B-block swizzle within a 128B Xt row (8 blocks): good for the staging
// scatter and the b128 frag reads (w = 16ni+l15).
__device__ __forceinline__ int swz(int w) { return (w ^ (w >> 2)) & 7; }

// out = A(56x56 circulant) * X(56x56) per plane, padded to 64^3, bf16 MFMA.
// R14: both HBM streams contiguous -> 58.0us.
// R16 (56.6): Xt stored bf16 -> B-frag is ONE ds_read_b128.
// R17 (54.1): persistent blocks, next-plane loads prefetched under MFMA.
// R18 (53.9, neutral): vmcnt drain at barrier wasn't the cost.
// R20 (53.7): quad staging (scatter 196->16 DS wave-instrs) -> DS not binding.
// R21 (56.0, REGRESSION): channel-persistence was fine (VALUBusy 9.8->6.6,
//   conflicts bit-identical -> A-frag never the conflict source) but
//   NBLK=1536 = 6 blocks/CU with 4 resident left the last generation at
//   HALF residency -> HBM stream unsaturated for ~1/3 of the kernel.
// R22 (this round): keep channel-persistence, fix residency: NBLK=3072
//   (12/CU = 3 full generations of 4). Everything else identical to R21.
// Ceiling model: fabric traffic 154MB read + 150.5MB write @ 6.29TB/s
//   copy ceiling -> 48.3us floor; best (R20) = 90%.
// waves_per_eu(4,4): the only codegen mode without the VGPR-24 pathology.
__global__ __launch_bounds__(256) __attribute__((amdgpu_waves_per_eu(4, 4)))
void parc_kernel(const float* __restrict__ x, const float* __restrict__ pe,
                 const float* __restrict__ wgt, const float* __restrict__ bias,
                 float* __restrict__ out)
{
    __shared__ __align__(16) unsigned short Xt16[64 * 64]; // [w][m] bf16, swizzled 16B blocks (8KB)
    __shared__ __align__(16) float Cb[56 * 60];            // [h][w] stride 60 dwords (13.4KB)
    __shared__ unsigned short wt2[112];                    // wt[k%56] bf16, single buffer

    const int t   = threadIdx.x;
    const int blk = blockIdx.x;
    const int c    = blk % Cc;                             // fixed channel for this block
    const int bgrp = blk / Cc;                             // 0..7
    const size_t bc0 = (size_t)(bgrp * NPL) * Cc + c;      // first plane; step = Cc

    // quad staging geometry (t<196): hg in 0..13, w4q in 0..13
    const int hg = t / NF4, w4q = t % NF4;
    const int Fq = 56 * hg + w4q;                          // f4 index of row 4hg, this w4
    const int kw = t >= Hh ? t - Hh : t;                   // weight dup index (t<112)
    const int l = t & 63, wvi = t >> 6, l15 = l & 15, g = l >> 4;

    // ---- one-time zeroing (scatter never touches these cells):
    //      (a) m-pad (logical m-block 7) of ALL rows: k>=56 terms exact 0.
    //      (b) w-pad rows 56..63 entirely: no garbage bf16 into MFMA.
    {
        const int w = t >> 2, j = t & 3;
        const int blkz = 7 ^ swz(w);                       // logical m-block 7
        *reinterpret_cast<u32*>((char*)Xt16 + 128 * w + 16 * blkz + 4 * j) = 0u;
        const int wz = 56 + (t >> 5);                      // rows 56..63, full 128B
        *reinterpret_cast<u32*>((char*)Xt16 + 128 * wz + 4 * (t & 31)) = 0u;
    }

    // ---- channel-constant loads (once per block) ----
    float p0 = 0.f, p1 = 0.f, p2 = 0.f, p3 = 0.f;
    if (t < 196) {
        const float* __restrict__ pec = pe + c * Hh;
        p0 = pec[4 * hg]; p1 = pec[4 * hg + 1]; p2 = pec[4 * hg + 2]; p3 = pec[4 * hg + 3];
    }
    const float bz = bias[c];
    if (t < 112) wt2[t] = (unsigned short)(cvtpk_bf16(wgt[c * Hh + kw], 0.f) & 0xffffu);

    f32x4 v0 = {}, v1 = {}, v2 = {}, v3 = {};

    // issue next-plane x loads (registers only; no LDS touch)
    #define ISSUE(BC) { \
        const f32x4* __restrict__ xin = reinterpret_cast<const f32x4*>(x) + (size_t)(BC) * (PLANE / 4); \
        if (t < 196) { \
            v0 = xin[Fq]; v1 = xin[Fq + 14]; v2 = xin[Fq + 28]; v3 = xin[Fq + 42]; \
        } }

    // scatter: 4 ds_write_b64 per thread (4 consecutive m per w-row),
    // conflict-free minimum (14 distinct (blk,sub8) pairs tile the banks)
    #define SCATTER() { \
        if (t < 196) { \
            const int blkb = hg >> 1, sub8 = 8 * (hg & 1); \
            _Pragma("unroll") \
            for (int q = 0; q < 4; ++q) { \
                const int w = 4 * w4q + q; \
                u32x2 d; \
                d[0] = cvtpk_bf16(v0[q] + p0, v1[q] + p1); \
                d[1] = cvtpk_bf16(v2[q] + p2, v3[q] + p3); \
                *reinterpret_cast<u32x2*>((char*)Xt16 + 128 * w + 16 * (blkb ^ swz(w)) + sub8) = d; \
            } \
        } }

    // ---- prologue: plane 0 ----
    ISSUE(bc0)
    SCATTER()
    __syncthreads();

    // ---- A-frags ONCE (loop-invariant: same channel all planes) ----
    // A[h][m] = wt[(m-h)%56]; lane row h=16wvi+l15, k(m)=8g+j+32step
    short8 afr[2];
    #pragma unroll
    for (int step = 0; step < 2; ++step) {
        #pragma unroll
        for (int j = 0; j < 8; ++j) {
            int idx = 32 * step + 8 * g + j - 16 * wvi - l15 + 56;
            idx = idx < 0 ? 0 : (idx > 111 ? 111 : idx);   // pad m>=56 hits zeroed X cols
            afr[step][j] = (short)wt2[idx];
        }
    }

    for (int it = 0; it < NPL; ++it) {
        const size_t bc_cur = bc0 + (size_t)it * Cc;

        // prefetch: next plane's x loads fly under MFMA + store phases
        if (it + 1 < NPL) { ISSUE(bc0 + (size_t)(it + 1) * Cc) }

        f32x4 acc[4];
        #pragma unroll
        for (int ni = 0; ni < 4; ++ni) acc[ni] = (f32x4){bz, bz, bz, bz};

        #pragma unroll
        for (int step = 0; step < 2; ++step) {
            #pragma unroll
            for (int ni = 0; ni < 4; ++ni) {
                const int w = 16 * ni + l15;              // B col n = l15
                const int blk0 = g + 4 * step;            // m0 = 8g+32step
                const short8 bfr = *reinterpret_cast<const short8*>(
                    (char*)Xt16 + 128 * w + 16 * (blk0 ^ swz(w)));
                acc[ni] = __builtin_amdgcn_mfma_f32_16x16x32_bf16(afr[step], bfr, acc[ni], 0, 0, 0);
            }
        }

        // ---- D (col=l15, row=4g+reg) -> Cb[h][w] (stride 60: 2-way banks) ----
        #pragma unroll
        for (int ni = 0; ni < 4; ++ni) {
            const int wcol = 16 * ni + l15;
            #pragma unroll
            for (int r = 0; r < 4; ++r) {
                const int h = 16 * wvi + 4 * g + r;
                if (h < Hh && wcol < Ww) Cb[60 * h + wcol] = acc[ni][r];
            }
        }
        __syncthreads();     // B2: Cb visible; plane-it Xt16 reads retired

        // ---- out stores: linear f4 => 1KB contiguous/wave-instr ----
        f4* __restrict__ op = reinterpret_cast<f4*>(out) + bc_cur * (PLANE / 4);
        #define GETST(U) { \
            const int rr = (U) / NF4, ww4 = (U) % NF4; \
            op[(U)] = *reinterpret_cast<const f4*>((char*)Cb + 240 * rr + 16 * ww4); }
        GETST(t)
        GETST(t + 256)
        GETST(t + 512)
        if (t < 16) { GETST(t + 768) }
        #undef GETST

        if (it + 1 < NPL) {
            SCATTER()            // prefetched loads land here (compiler vmcnt wait)
            __syncthreads();     // B1: Xt16 visible; Cb reads retired before next writes
        }
    }
    #undef SCATTER
    #undef ISSUE
}

extern "C" void kernel_launch(void* const* d_in, const int* in_sizes, int n_in,
                              void* d_out, int out_size, void* d_ws, size_t ws_size,
                              hipStream_t stream) {
    const float* x  = (const float*)d_in[0];
    const float* pe = (const float*)d_in[1];
    const float* w  = (const float*)d_in[2];
    const float* b  = (const float*)d_in[3];
    float* out      = (float*)d_out;

    parc_kernel<<<dim3(NBLK), 256, 0, stream>>>(x, pe, w, b, out);
}

// Round 9
// 54.485 us; speedup vs baseline: 1.0269x; 1.0067x over previous
//
#include <hip/hip_runtime.h>

#define Cc 384
#define Hh 56
#define Ww 56
#define PLANE (Hh*Ww)        // 3136 floats
#define NF4 14               // float4s per row
#define NBLK 1024            // EXACTLY 4 blocks/CU, all resident, zero churn
#define NPL 12               // planes per block: 1024*12 = 12288

typedef short short8 __attribute__((ext_vector_type(8)));
typedef float f32x4  __attribute__((ext_vector_type(4)));
typedef unsigned int u32;
typedef u32 u32x2 __attribute__((ext_vector_type(2)));
struct __align__(16) f4 { float x, y, z, w; };

__device__ __forceinline__ u32 cvtpk_bf16(float a, float b) {
    u32 d; asm("v_cvt_pk_bf16_f32 %0, %1, %2" : "=v"(d) : "v"(a), "v"(b));
    return d;   // lo=bf16(a), hi=bf16(b), RNE
}
// 16B-block swizzle within a 128B Xt row (8 blocks): good for the staging
// scatter and the b128 frag reads (w = 16ni+l15).
__device__ __forceinline__ int swz(int w) { return (w ^ (w >> 2)) & 7; }

// out = A(56x56 circulant) * X(56x56) per plane, padded to 64^3, bf16 MFMA.
// R14: both HBM streams contiguous -> 58.0us.
// R16 (56.6): Xt stored bf16 -> B-frag is ONE ds_read_b128.
// R17 (54.1): persistent blocks (2048x6), next-plane loads under MFMA.
// R18 (53.9, neutral): vmcnt drain at barrier wasn't the cost.
// R20 (53.7, BEST): quad staging (scatter 196->16 DS instrs) -> DS not binding.
// R21 (56.0) / R22 (54.85): channel-persistence neutral-to-negative; the
//   regressions tracked GENERATION COUNT (3 gens = 3 cold starts, 3/4
//   prefetch coverage). Only the memory stream's duty cycle matters.
// R23 (this round): R20 structure VERBATIM, one variable: NBLK=1024/NPL=12
//   -> 4 blocks/CU resident for the whole kernel, ZERO churn, 1 cold start
//   (vs 2), 11/12 planes prefetched (vs 5/6).
// Ceiling model: fabric 154MB read + 150.5MB write @ 6.29TB/s -> 48.3us
//   floor; R20 = 90%. Pre-committed: <1% gain here -> ROOFLINE.
// waves_per_eu(4,4): the only codegen mode without the VGPR-24 pathology.
__global__ __launch_bounds__(256) __attribute__((amdgpu_waves_per_eu(4, 4)))
void parc_kernel(const float* __restrict__ x, const float* __restrict__ pe,
                 const float* __restrict__ wgt, const float* __restrict__ bias,
                 float* __restrict__ out)
{
    __shared__ __align__(16) unsigned short Xt16[64 * 64]; // [w][m] bf16, swizzled 16B blocks (8KB)
    __shared__ __align__(16) float Cb[56 * 60];            // [h][w] stride 60 dwords (13.4KB)
    __shared__ unsigned short wt2[2][112];                 // wt[k%56] bf16, double-buffered

    const int t   = threadIdx.x;
    const int blk = blockIdx.x;

    // quad staging geometry (t<196): hg in 0..13, w4q in 0..13
    const int hg = t / NF4, w4q = t % NF4;
    const int Fq = 56 * hg + w4q;                          // f4 index of row 4hg, this w4
    const int kw = t >= Hh ? t - Hh : t;                   // weight dup index (t<112)
    const int l = t & 63, wvi = t >> 6, l15 = l & 15, g = l >> 4;

    // ---- one-time zeroing (scatter never touches these cells):
    //      (a) m-pad (logical m-block 7) of ALL rows: k>=56 terms exact 0.
    //      (b) w-pad rows 56..63 entirely: no garbage/NaN bf16 into MFMA.
    {
        const int w = t >> 2, j = t & 3;
        const int blkz = 7 ^ swz(w);                       // logical m-block 7
        *reinterpret_cast<u32*>((char*)Xt16 + 128 * w + 16 * blkz + 4 * j) = 0u;
        const int wz = 56 + (t >> 5);                      // rows 56..63, full 128B
        *reinterpret_cast<u32*>((char*)Xt16 + 128 * wz + 4 * (t & 31)) = 0u;
    }

    f32x4 v0 = {}, v1 = {}, v2 = {}, v3 = {};
    float p0 = 0.f, p1 = 0.f, p2 = 0.f, p3 = 0.f, wld = 0.f, bz = 0.f;

    // issue next-plane global loads (registers only; no LDS touch)
    #define ISSUE(BC) { \
        const f32x4* __restrict__ xin = reinterpret_cast<const f32x4*>(x) + (size_t)(BC) * (PLANE / 4); \
        const int c_ = (BC) % Cc; \
        const float* __restrict__ pec = pe + c_ * Hh; \
        if (t < 196) { \
            v0 = xin[Fq]; v1 = xin[Fq + 14]; v2 = xin[Fq + 28]; v3 = xin[Fq + 42]; \
            p0 = pec[4 * hg]; p1 = pec[4 * hg + 1]; p2 = pec[4 * hg + 2]; p3 = pec[4 * hg + 3]; \
        } \
        if (t < 112) wld = wgt[c_ * Hh + kw]; \
        bz = bias[c_]; }

    // scatter: 4 ds_write_b64 per thread (4 consecutive m per w-row),
    // conflict-free minimum (14 distinct (blk,sub8) pairs tile the banks)
    #define SCATTER(PAR) { \
        if (t < 112) wt2[PAR][t] = (unsigned short)(cvtpk_bf16(wld, wld) & 0xffffu); \
        if (t < 196) { \
            const int blkb = hg >> 1, sub8 = 8 * (hg & 1); \
            _Pragma("unroll") \
            for (int q = 0; q < 4; ++q) { \
                const int w = 4 * w4q + q; \
                u32x2 d; \
                d[0] = cvtpk_bf16(v0[q] + p0, v1[q] + p1); \
                d[1] = cvtpk_bf16(v2[q] + p2, v3[q] + p3); \
                *reinterpret_cast<u32x2*>((char*)Xt16 + 128 * w + 16 * (blkb ^ swz(w)) + sub8) = d; \
            } \
        } }

    // ---- prologue: plane 0 ----
    ISSUE(blk)
    SCATTER(0)
    float bzc = bz;
    __syncthreads();

    for (int it = 0; it < NPL; ++it) {
        const int par = it & 1;
        const size_t bc_cur = (size_t)blk + (size_t)NBLK * it;

        // A-frags: A[h][m] = wt[(m-h)%56]; lane row h=16wvi+l15, k(m)=8g+j+32step
        short8 afr[2];
        #pragma unroll
        for (int step = 0; step < 2; ++step) {
            #pragma unroll
            for (int j = 0; j < 8; ++j) {
                int idx = 32 * step + 8 * g + j - 16 * wvi - l15 + 56;
                idx = idx < 0 ? 0 : (idx > 111 ? 111 : idx);   // pad m>=56 hits zeroed X cols
                afr[step][j] = (short)wt2[par][idx];
            }
        }

        // prefetch: next plane's loads fly under MFMA + store phases
        if (it + 1 < NPL) { ISSUE((size_t)blk + (size_t)NBLK * (it + 1)) }

        f32x4 acc[4];
        #pragma unroll
        for (int ni = 0; ni < 4; ++ni) acc[ni] = (f32x4){bzc, bzc, bzc, bzc};

        #pragma unroll
        for (int step = 0; step < 2; ++step) {
            #pragma unroll
            for (int ni = 0; ni < 4; ++ni) {
                const int w = 16 * ni + l15;              // B col n = l15
                const int blk0 = g + 4 * step;            // m0 = 8g+32step
                const short8 bfr = *reinterpret_cast<const short8*>(
                    (char*)Xt16 + 128 * w + 16 * (blk0 ^ swz(w)));
                acc[ni] = __builtin_amdgcn_mfma_f32_16x16x32_bf16(afr[step], bfr, acc[ni], 0, 0, 0);
            }
        }

        // ---- D (col=l15, row=4g+reg) -> Cb[h][w] (stride 60: 2-way banks) ----
        #pragma unroll
        for (int ni = 0; ni < 4; ++ni) {
            const int wcol = 16 * ni + l15;
            #pragma unroll
            for (int r = 0; r < 4; ++r) {
                const int h = 16 * wvi + 4 * g + r;
                if (h < Hh && wcol < Ww) Cb[60 * h + wcol] = acc[ni][r];
            }
        }
        __syncthreads();     // B2: Cb visible; plane-it Xt16/wt2 reads retired

        // ---- out stores: linear f4 => 1KB contiguous/wave-instr ----
        f4* __restrict__ op = reinterpret_cast<f4*>(out) + bc_cur * (PLANE / 4);
        #define GETST(U) { \
            const int rr = (U) / NF4, ww4 = (U) % NF4; \
            op[(U)] = *reinterpret_cast<const f4*>((char*)Cb + 240 * rr + 16 * ww4); }
        GETST(t)
        GETST(t + 256)
        GETST(t + 512)
        if (t < 16) { GETST(t + 768) }
        #undef GETST

        if (it + 1 < NPL) {
            SCATTER(par ^ 1)     // prefetched loads land here (compiler vmcnt wait)
            bzc = bz;
            __syncthreads();     // B1: Xt16/wt2 visible; Cb reads retired before next writes
        }
    }
    #undef SCATTER
    #undef ISSUE
}

extern "C" void kernel_launch(void* const* d_in, const int* in_sizes, int n_in,
                              void* d_out, int out_size, void* d_ws, size_t ws_size,
                              hipStream_t stream) {
    const float* x  = (const float*)d_in[0];
    const float* pe = (const float*)d_in[1];
    const float* w  = (const float*)d_in[2];
    const float* b  = (const float*)d_in[3];
    float* out      = (float*)d_out;

    parc_kernel<<<dim3(NBLK), 256, 0, stream>>>(x, pe, w, b, out);
}

// Round 10
// 54.265 us; speedup vs baseline: 1.0311x; 1.0041x over previous
//
#include <hip/hip_runtime.h>

#define Cc 384
#define Hh 56
#define Ww 56
#define PLANE (Hh*Ww)        // 3136 floats
#define NF4 14               // float4s per row
#define NBLK 2048            // persistent-ish grid
#define NPL 6                // planes per block: 2048*6 = 12288

typedef short short8 __attribute__((ext_vector_type(8)));
typedef float f32x4  __attribute__((ext_vector_type(4)));
typedef unsigned int u32;
typedef u32 u32x2 __attribute__((ext_vector_type(2)));
struct __align__(16) f4 { float x, y, z, w; };

__device__ __forceinline__ u32 cvtpk_bf16(float a, float b) {
    u32 d; asm("v_cvt_pk_bf16_f32 %0, %1, %2" : "=v"(d) : "v"(a), "v"(b));
    return d;   // lo=bf16(a), hi=bf16(b), RNE
}
// 16B-block swizzle within a 128B Xt row (8 blocks): good for the staging
// scatter and the b128 frag reads (w = 16ni+l15).
__device__ __forceinline__ int swz(int w) { return (w ^ (w >> 2)) & 7; }

// out = A(56x56 circulant) * X(56x56) per plane, padded to 64^3, bf16 MFMA.
// FINAL (R24 = R20 verbatim, best measured 53.7us = 90% of the 48.3us
// mixed-stream fabric floor: 154MB read [half L3-absorbed] + 150.5MB write
// @ 6.29TB/s copy ceiling).
// Ladder: R14 58.0 (contiguous HBM streams) -> R16 56.6 (bf16 Xt, 1 b128
// B-frag) -> R17 54.1 (persistent 2048x6 + prefetch) -> R20 53.7 (quad
// staging: 16 ds_write_b64/block).
// Measured-neutral/negative levers (all ruled out): lgkmcnt-only barrier
// (R18), DS-traffic cuts beyond R20 (R20 itself moved only 0.3%),
// channel-persistence (R21/R22), zero-churn 1024x12 (R23), transposed
// MFMA decomposition (R15), occupancy raises (R13). The binding resource
// is the mixed read+write memory stream's achievable duty cycle.
// waves_per_eu(4,4): the only codegen mode without the VGPR-24 pathology.
__global__ __launch_bounds__(256) __attribute__((amdgpu_waves_per_eu(4, 4)))
void parc_kernel(const float* __restrict__ x, const float* __restrict__ pe,
                 const float* __restrict__ wgt, const float* __restrict__ bias,
                 float* __restrict__ out)
{
    __shared__ __align__(16) unsigned short Xt16[64 * 64]; // [w][m] bf16, swizzled 16B blocks (8KB)
    __shared__ __align__(16) float Cb[56 * 60];            // [h][w] stride 60 dwords (13.4KB)
    __shared__ unsigned short wt2[2][112];                 // wt[k%56] bf16, double-buffered

    const int t   = threadIdx.x;
    const int blk = blockIdx.x;

    // quad staging geometry (t<196): hg in 0..13, w4q in 0..13
    const int hg = t / NF4, w4q = t % NF4;
    const int Fq = 56 * hg + w4q;                          // f4 index of row 4hg, this w4
    const int kw = t >= Hh ? t - Hh : t;                   // weight dup index (t<112)
    const int l = t & 63, wvi = t >> 6, l15 = l & 15, g = l >> 4;

    // ---- one-time zeroing (scatter never touches these cells):
    //      (a) m-pad (logical m-block 7) of ALL rows: k>=56 terms exact 0.
    //      (b) w-pad rows 56..63 entirely: no garbage/NaN bf16 into MFMA.
    {
        const int w = t >> 2, j = t & 3;
        const int blkz = 7 ^ swz(w);                       // logical m-block 7
        *reinterpret_cast<u32*>((char*)Xt16 + 128 * w + 16 * blkz + 4 * j) = 0u;
        const int wz = 56 + (t >> 5);                      // rows 56..63, full 128B
        *reinterpret_cast<u32*>((char*)Xt16 + 128 * wz + 4 * (t & 31)) = 0u;
    }

    f32x4 v0 = {}, v1 = {}, v2 = {}, v3 = {};
    float p0 = 0.f, p1 = 0.f, p2 = 0.f, p3 = 0.f, wld = 0.f, bz = 0.f;

    // issue next-plane global loads (registers only; no LDS touch)
    #define ISSUE(BC) { \
        const f32x4* __restrict__ xin = reinterpret_cast<const f32x4*>(x) + (size_t)(BC) * (PLANE / 4); \
        const int c_ = (BC) % Cc; \
        const float* __restrict__ pec = pe + c_ * Hh; \
        if (t < 196) { \
            v0 = xin[Fq]; v1 = xin[Fq + 14]; v2 = xin[Fq + 28]; v3 = xin[Fq + 42]; \
            p0 = pec[4 * hg]; p1 = pec[4 * hg + 1]; p2 = pec[4 * hg + 2]; p3 = pec[4 * hg + 3]; \
        } \
        if (t < 112) wld = wgt[c_ * Hh + kw]; \
        bz = bias[c_]; }

    // scatter: 4 ds_write_b64 per thread (4 consecutive m per w-row),
    // conflict-free minimum (4 dwords/bank-group; 14 distinct (blk,sub8) pairs)
    #define SCATTER(PAR) { \
        if (t < 112) wt2[PAR][t] = (unsigned short)(cvtpk_bf16(wld, wld) & 0xffffu); \
        if (t < 196) { \
            const int blkb = hg >> 1, sub8 = 8 * (hg & 1); \
            _Pragma("unroll") \
            for (int q = 0; q < 4; ++q) { \
                const int w = 4 * w4q + q; \
                u32x2 d; \
                d[0] = cvtpk_bf16(v0[q] + p0, v1[q] + p1); \
                d[1] = cvtpk_bf16(v2[q] + p2, v3[q] + p3); \
                *reinterpret_cast<u32x2*>((char*)Xt16 + 128 * w + 16 * (blkb ^ swz(w)) + sub8) = d; \
            } \
        } }

    // ---- prologue: plane 0 ----
    ISSUE(blk)
    SCATTER(0)
    float bzc = bz;
    __syncthreads();

    for (int it = 0; it < NPL; ++it) {
        const int par = it & 1;
        const int bc_cur = blk + NBLK * it;

        // A-frags: A[h][m] = wt[(m-h)%56]; lane row h=16wvi+l15, k(m)=8g+j+32step
        short8 afr[2];
        #pragma unroll
        for (int step = 0; step < 2; ++step) {
            #pragma unroll
            for (int j = 0; j < 8; ++j) {
                int idx = 32 * step + 8 * g + j - 16 * wvi - l15 + 56;
                idx = idx < 0 ? 0 : (idx > 111 ? 111 : idx);   // pad m>=56 hits zeroed X cols
                afr[step][j] = (short)wt2[par][idx];
            }
        }

        // prefetch: next plane's loads fly under MFMA + store phases
        if (it + 1 < NPL) { ISSUE(blk + NBLK * (it + 1)) }

        f32x4 acc[4];
        #pragma unroll
        for (int ni = 0; ni < 4; ++ni) acc[ni] = (f32x4){bzc, bzc, bzc, bzc};

        #pragma unroll
        for (int step = 0; step < 2; ++step) {
            #pragma unroll
            for (int ni = 0; ni < 4; ++ni) {
                const int w = 16 * ni + l15;              // B col n = l15
                const int blk0 = g + 4 * step;            // m0 = 8g+32step
                const short8 bfr = *reinterpret_cast<const short8*>(
                    (char*)Xt16 + 128 * w + 16 * (blk0 ^ swz(w)));
                acc[ni] = __builtin_amdgcn_mfma_f32_16x16x32_bf16(afr[step], bfr, acc[ni], 0, 0, 0);
            }
        }

        // ---- D (col=l15, row=4g+reg) -> Cb[h][w] (stride 60: 2-way banks) ----
        #pragma unroll
        for (int ni = 0; ni < 4; ++ni) {
            const int wcol = 16 * ni + l15;
            #pragma unroll
            for (int r = 0; r < 4; ++r) {
                const int h = 16 * wvi + 4 * g + r;
                if (h < Hh && wcol < Ww) Cb[60 * h + wcol] = acc[ni][r];
            }
        }
        __syncthreads();     // B2: Cb visible; plane-it Xt16/wt2 reads retired

        // ---- out stores: linear f4 => 1KB contiguous/wave-instr ----
        f4* __restrict__ op = reinterpret_cast<f4*>(out) + (size_t)bc_cur * (PLANE / 4);
        #define GETST(U) { \
            const int rr = (U) / NF4, ww4 = (U) % NF4; \
            op[(U)] = *reinterpret_cast<const f4*>((char*)Cb + 240 * rr + 16 * ww4); }
        GETST(t)
        GETST(t + 256)
        GETST(t + 512)
        if (t < 16) { GETST(t + 768) }
        #undef GETST

        if (it + 1 < NPL) {
            SCATTER(par ^ 1)     // prefetched loads land here (compiler vmcnt wait)
            bzc = bz;
            __syncthreads();     // B1: Xt16/wt2 visible; Cb reads retired before next writes
        }
    }
    #undef SCATTER
    #undef ISSUE
}

extern "C" void kernel_launch(void* const* d_in, const int* in_sizes, int n_in,
                              void* d_out, int out_size, void* d_ws, size_t ws_size,
                              hipStream_t stream) {
    const float* x  = (const float*)d_in[0];
    const float* pe = (const float*)d_in[1];
    const float* w  = (const float*)d_in[2];
    const float* b  = (const float*)d_in[3];
    float* out      = (float*)d_out;

    parc_kernel<<<dim3(NBLK), 256, 0, stream>>>(x, pe, w, b, out);
}